// Round 1
// baseline (300.432 us; speedup 1.0000x reference)
//
#include <hip/hip_runtime.h>
#include <hip/hip_bf16.h>

typedef __bf16 bf16_t;
typedef __bf16 bf16x8 __attribute__((ext_vector_type(8)));
typedef __bf16 bf16x4 __attribute__((ext_vector_type(4)));
typedef float  f32x4  __attribute__((ext_vector_type(4)));

#define D_DIM 768
#define S_DIM 2048
#define B_DIM 8
#define M_TOT (B_DIM * S_DIM)   // 16384
#define BK 32
#define LDS_PAD 40              // 32 + 8 bf16 -> 80B row stride (16B aligned, conflict-spreading)

// ---------------- Kernel 0: weight transpose + bf16 cast ----------------
// Wt[n][k] = bf16(W[k][n]); z selects q/k weight.
__global__ __launch_bounds__(256)
void transpose_weights(const float* __restrict__ Wq, const float* __restrict__ Wk,
                       bf16_t* __restrict__ Wqt, bf16_t* __restrict__ Wkt) {
    __shared__ float tile[32][33];
    const float* W  = blockIdx.z ? Wk  : Wq;
    bf16_t*      Wt = blockIdx.z ? Wkt : Wqt;
    int tx = threadIdx.x & 31, ty = threadIdx.x >> 5;   // 32 x 8
    int bx = blockIdx.x, by = blockIdx.y;
#pragma unroll
    for (int i = 0; i < 4; i++) {
        int k = bx * 32 + ty + i * 8;
        int n = by * 32 + tx;
        tile[ty + i * 8][tx] = W[k * D_DIM + n];
    }
    __syncthreads();
#pragma unroll
    for (int i = 0; i < 4; i++) {
        int n = by * 32 + ty + i * 8;
        int k = bx * 32 + tx;
        Wt[n * D_DIM + k] = (bf16_t)tile[tx][ty + i * 8];
    }
}

// ---------------- Kernel 1: projection GEMM ----------------
// Out[m][n] = bf16( sum_k X[m][k] * Wt[n][k] + bias[n] ), M=16384, N=K=768
__global__ __launch_bounds__(256)
void proj_gemm(const float* __restrict__ X, const bf16_t* __restrict__ Wt,
               const float* __restrict__ bias, bf16_t* __restrict__ Out) {
    __shared__ bf16_t lds_a[128][LDS_PAD];
    __shared__ bf16_t lds_b[128][LDS_PAD];

    const int m0 = blockIdx.y * 128;
    const int n0 = blockIdx.x * 128;
    const int tid  = threadIdx.x;
    const int lane = tid & 63;
    const int wid  = tid >> 6;
    const int wm   = wid & 1;        // wave row (m)
    const int wn   = wid >> 1;       // wave col (n)
    const int lrow = lane & 15;
    const int quad = lane >> 4;

    f32x4 acc[4][4];
#pragma unroll
    for (int i = 0; i < 4; i++)
#pragma unroll
        for (int j = 0; j < 4; j++) acc[i][j] = (f32x4){0.f, 0.f, 0.f, 0.f};

    const int ar = tid >> 3, ac = tid & 7;   // A staging: 32 rows x 8 float4 chunks
    const int br = tid >> 2, bc = tid & 3;   // B staging: 64 rows x 4 16B chunks

    for (int k0 = 0; k0 < D_DIM; k0 += BK) {
        // stage A (fp32 -> bf16)
#pragma unroll
        for (int p = 0; p < 4; p++) {
            int row = ar + p * 32;
            const float4 v = *(const float4*)(X + (size_t)(m0 + row) * D_DIM + k0 + ac * 4);
            bf16x4 b;
            b[0] = (bf16_t)v.x; b[1] = (bf16_t)v.y; b[2] = (bf16_t)v.z; b[3] = (bf16_t)v.w;
            *(bf16x4*)&lds_a[row][ac * 4] = b;
        }
        // stage B (bf16 copy)
#pragma unroll
        for (int p = 0; p < 2; p++) {
            int row = br + p * 64;
            *(uint4*)&lds_b[row][bc * 8] =
                *(const uint4*)(Wt + (size_t)(n0 + row) * D_DIM + k0 + bc * 8);
        }
        __syncthreads();

        bf16x8 af[4], bfr[4];
#pragma unroll
        for (int f = 0; f < 4; f++) {
            af[f]  = *(const bf16x8*)&lds_a[wm * 64 + f * 16 + lrow][quad * 8];
            bfr[f] = *(const bf16x8*)&lds_b[wn * 64 + f * 16 + lrow][quad * 8];
        }
#pragma unroll
        for (int fm = 0; fm < 4; fm++)
#pragma unroll
            for (int fn = 0; fn < 4; fn++)
                acc[fm][fn] = __builtin_amdgcn_mfma_f32_16x16x32_bf16(
                    af[fm], bfr[fn], acc[fm][fn], 0, 0, 0);
        __syncthreads();
    }

    // epilogue: bias + bf16 store. C layout: col=lane&15, row=quad*4+reg
#pragma unroll
    for (int fn = 0; fn < 4; fn++) {
        int col = n0 + wn * 64 + fn * 16 + lrow;
        float bv = bias[col];
#pragma unroll
        for (int fm = 0; fm < 4; fm++) {
            int rbase = m0 + wm * 64 + fm * 16 + quad * 4;
#pragma unroll
            for (int r = 0; r < 4; r++)
                Out[(size_t)(rbase + r) * D_DIM + col] = (bf16_t)(acc[fm][fn][r] + bv);
        }
    }
}

// ---------------- Kernel 2: qk tile + w=exp(tanh) + column reduce ----------------
__global__ __launch_bounds__(256)
void attn_reduce(const bf16_t* __restrict__ Q, const bf16_t* __restrict__ K,
                 float* __restrict__ num, float* __restrict__ den) {
    __shared__ bf16_t lds_a[128][LDS_PAD];
    __shared__ bf16_t lds_b[128][LDS_PAD];
    __shared__ float red[2][2][128];   // [w|wv][wm][col]

    const int b  = blockIdx.z;
    const int s0 = blockIdx.y * 128;
    const int t0 = blockIdx.x * 128;
    const bf16_t* Qb = Q + (size_t)b * S_DIM * D_DIM;
    const bf16_t* Kb = K + (size_t)b * S_DIM * D_DIM;

    const int tid  = threadIdx.x;
    const int lane = tid & 63;
    const int wid  = tid >> 6;
    const int wm   = wid & 1;
    const int wn   = wid >> 1;
    const int lrow = lane & 15;
    const int quad = lane >> 4;

    f32x4 acc[4][4];
#pragma unroll
    for (int i = 0; i < 4; i++)
#pragma unroll
        for (int j = 0; j < 4; j++) acc[i][j] = (f32x4){0.f, 0.f, 0.f, 0.f};

    const int br = tid >> 2, bc = tid & 3;   // both tiles bf16: 64 rows x 4 chunks

    for (int k0 = 0; k0 < D_DIM; k0 += BK) {
#pragma unroll
        for (int p = 0; p < 2; p++) {
            int row = br + p * 64;
            *(uint4*)&lds_a[row][bc * 8] =
                *(const uint4*)(Qb + (size_t)(s0 + row) * D_DIM + k0 + bc * 8);
            *(uint4*)&lds_b[row][bc * 8] =
                *(const uint4*)(Kb + (size_t)(t0 + row) * D_DIM + k0 + bc * 8);
        }
        __syncthreads();

        bf16x8 af[4], bfr[4];
#pragma unroll
        for (int f = 0; f < 4; f++) {
            af[f]  = *(const bf16x8*)&lds_a[wm * 64 + f * 16 + lrow][quad * 8];
            bfr[f] = *(const bf16x8*)&lds_b[wn * 64 + f * 16 + lrow][quad * 8];
        }
#pragma unroll
        for (int fm = 0; fm < 4; fm++)
#pragma unroll
            for (int fn = 0; fn < 4; fn++)
                acc[fm][fn] = __builtin_amdgcn_mfma_f32_16x16x32_bf16(
                    af[fm], bfr[fn], acc[fm][fn], 0, 0, 0);
        __syncthreads();
    }

    // elementwise w = exp(tanh(qk)); per-column (t) partial sums over the 64 s-rows
    float sw[4], swv[4];
#pragma unroll
    for (int fn = 0; fn < 4; fn++) { sw[fn] = 0.f; swv[fn] = 0.f; }
#pragma unroll
    for (int fm = 0; fm < 4; fm++)
#pragma unroll
        for (int fn = 0; fn < 4; fn++)
#pragma unroll
            for (int r = 0; r < 4; r++) {
                float v = acc[fm][fn][r];
                // tanh(v) = 1 - 2/(exp(2v)+1); saturates gracefully (inf -> 1)
                float e2 = __expf(2.f * v);
                float t  = 1.f - 2.f / (e2 + 1.f);
                float w  = __expf(t);
                sw[fn]  += w;
                swv[fn] += w * v;
            }
    // butterfly over quads (rows within a 16-row fragment group)
#pragma unroll
    for (int fn = 0; fn < 4; fn++) {
        sw[fn]  += __shfl_xor(sw[fn], 16);  sw[fn]  += __shfl_xor(sw[fn], 32);
        swv[fn] += __shfl_xor(swv[fn], 16); swv[fn] += __shfl_xor(swv[fn], 32);
    }
    if (quad == 0) {
#pragma unroll
        for (int fn = 0; fn < 4; fn++) {
            red[0][wm][wn * 64 + fn * 16 + lrow] = sw[fn];
            red[1][wm][wn * 64 + fn * 16 + lrow] = swv[fn];
        }
    }
    __syncthreads();
    if (tid < 128) {
        int t = t0 + tid;
        atomicAdd(&den[b * S_DIM + t], red[0][0][tid] + red[0][1][tid]);
        atomicAdd(&num[b * S_DIM + t], red[1][0][tid] + red[1][1][tid]);
    }
}

// ---------------- Kernel 3: finalize ----------------
__global__ __launch_bounds__(256)
void finalize(const float* __restrict__ num, const float* __restrict__ den,
              float* __restrict__ out, int n) {
    int i = blockIdx.x * 256 + threadIdx.x;
    if (i < n) out[i] = num[i] / (den[i] + 1e-7f);
}

extern "C" void kernel_launch(void* const* d_in, const int* in_sizes, int n_in,
                              void* d_out, int out_size, void* d_ws, size_t ws_size,
                              hipStream_t stream) {
    (void)in_sizes; (void)n_in; (void)out_size; (void)ws_size;
    const float* x1 = (const float*)d_in[0];
    const float* x2 = (const float*)d_in[1];
    const float* Wq = (const float*)d_in[2];
    const float* bq = (const float*)d_in[3];
    const float* Wk = (const float*)d_in[4];
    const float* bk = (const float*)d_in[5];
    float* out = (float*)d_out;

    char* ws = (char*)d_ws;
    size_t off = 0;
    bf16_t* qb  = (bf16_t*)(ws + off); off += (size_t)M_TOT * D_DIM * 2;   // 25.2 MB
    bf16_t* kb  = (bf16_t*)(ws + off); off += (size_t)M_TOT * D_DIM * 2;   // 25.2 MB
    bf16_t* Wqt = (bf16_t*)(ws + off); off += (size_t)D_DIM * D_DIM * 2;
    bf16_t* Wkt = (bf16_t*)(ws + off); off += (size_t)D_DIM * D_DIM * 2;
    float*  num = (float*)(ws + off);  off += (size_t)M_TOT * 4;
    float*  den = (float*)(ws + off);  off += (size_t)M_TOT * 4;

    // num/den are contiguous: one async memset (ws is re-poisoned before every launch)
    hipMemsetAsync(num, 0, (size_t)M_TOT * 4 * 2, stream);

    transpose_weights<<<dim3(24, 24, 2), 256, 0, stream>>>(Wq, Wk, Wqt, Wkt);
    proj_gemm<<<dim3(6, 128), 256, 0, stream>>>(x1, Wqt, bq, qb);
    proj_gemm<<<dim3(6, 128), 256, 0, stream>>>(x2, Wkt, bk, kb);
    attn_reduce<<<dim3(16, 16, 8), 256, 0, stream>>>(qb, kb, num, den);
    finalize<<<dim3((M_TOT + 255) / 256), 256, 0, stream>>>(num, den, out, M_TOT);
}

// Round 2
// 281.128 us; speedup vs baseline: 1.0687x; 1.0687x over previous
//
#include <hip/hip_runtime.h>
#include <hip/hip_bf16.h>

typedef __bf16 bf16_t;
typedef __bf16 bf16x8 __attribute__((ext_vector_type(8)));
typedef __bf16 bf16x4 __attribute__((ext_vector_type(4)));
typedef float  f32x4  __attribute__((ext_vector_type(4)));

#define D_DIM 768
#define S_DIM 2048
#define B_DIM 8
#define M_TOT (B_DIM * S_DIM)   // 16384
#define BK 32

// async global->LDS, 16B per lane. LDS dest = wave-uniform base + lane*16B
// (m104/m108: per-lane LDS scatter is NOT possible -> unpadded row-major tiles).
#define GLOAD_LDS16(g, l) __builtin_amdgcn_global_load_lds( \
    (const __attribute__((address_space(1))) unsigned int*)(g), \
    (__attribute__((address_space(3))) unsigned int*)(l), 16, 0, 0)

// ---------------- Kernel A: fp32 -> bf16 cast of x1/x2 ----------------
__global__ __launch_bounds__(256)
void cast_inputs(const float* __restrict__ x1, const float* __restrict__ x2,
                 bf16_t* __restrict__ o1, bf16_t* __restrict__ o2) {
    const float* x = blockIdx.z ? x2 : x1;
    bf16_t*      o = blockIdx.z ? o2 : o1;
    size_t i = ((size_t)blockIdx.x * 256 + threadIdx.x) * 8;  // grid sized exactly
    float4 a = *(const float4*)(x + i);
    float4 b = *(const float4*)(x + i + 4);
    bf16x8 r;
    r[0] = (bf16_t)a.x; r[1] = (bf16_t)a.y; r[2] = (bf16_t)a.z; r[3] = (bf16_t)a.w;
    r[4] = (bf16_t)b.x; r[5] = (bf16_t)b.y; r[6] = (bf16_t)b.z; r[7] = (bf16_t)b.w;
    *(bf16x8*)(o + i) = r;
}

// ---------------- Kernel B: weight transpose + bf16 cast ----------------
__global__ __launch_bounds__(256)
void transpose_weights(const float* __restrict__ Wq, const float* __restrict__ Wk,
                       bf16_t* __restrict__ Wqt, bf16_t* __restrict__ Wkt) {
    __shared__ float tile[32][33];
    const float* W  = blockIdx.z ? Wk  : Wq;
    bf16_t*      Wt = blockIdx.z ? Wkt : Wqt;
    int tx = threadIdx.x & 31, ty = threadIdx.x >> 5;   // 32 x 8
    int bx = blockIdx.x, by = blockIdx.y;
#pragma unroll
    for (int i = 0; i < 4; i++) {
        int k = bx * 32 + ty + i * 8;
        int n = by * 32 + tx;
        tile[ty + i * 8][tx] = W[k * D_DIM + n];
    }
    __syncthreads();
#pragma unroll
    for (int i = 0; i < 4; i++) {
        int n = by * 32 + ty + i * 8;
        int k = bx * 32 + tx;
        Wt[n * D_DIM + k] = (bf16_t)tile[tx][ty + i * 8];
    }
}

// ---------------- Kernel C: projection GEMM (m97 structure) ----------------
// Out[m][n] = bf16( sum_k Xb[m][k] * Wt[n][k] + bias[n] ); z picks q/k.
__global__ __launch_bounds__(256)
void proj_gemm(const bf16_t* __restrict__ x1b, const bf16_t* __restrict__ x2b,
               const bf16_t* __restrict__ Wqt, const bf16_t* __restrict__ Wkt,
               const float* __restrict__ bq, const float* __restrict__ bk,
               bf16_t* __restrict__ qb, bf16_t* __restrict__ kb) {
    __shared__ bf16_t lds_a[128 * BK];   // 8 KB, unpadded (global_load_lds layout)
    __shared__ bf16_t lds_b[128 * BK];

    const bf16_t* X    = blockIdx.z ? x2b : x1b;
    const bf16_t* Wt   = blockIdx.z ? Wkt : Wqt;
    const float*  bias = blockIdx.z ? bk  : bq;
    bf16_t*       Out  = blockIdx.z ? kb  : qb;

    const int m0 = blockIdx.y * 128;
    const int n0 = blockIdx.x * 128;
    const int tid  = threadIdx.x;
    const int lane = tid & 63;
    const int wid  = tid >> 6;
    const int wm   = wid & 1;
    const int wn   = wid >> 1;
    const int lrow = lane & 15;
    const int quad = lane >> 4;

    f32x4 acc[4][4];
#pragma unroll
    for (int i = 0; i < 4; i++)
#pragma unroll
        for (int j = 0; j < 4; j++) acc[i][j] = (f32x4){0.f, 0.f, 0.f, 0.f};

    // staging geometry: wave wid stages rows [wid*32, wid*32+32) of each tile,
    // two 16-row chunks per tile; lane l -> row +(l>>2), col (l&3)*8 elems.
    const int srow = wid * 32 + (lane >> 2);
    const int scol = (lane & 3) * 8;
    const bf16_t* ag = X  + (size_t)(m0 + srow) * D_DIM + scol;
    const bf16_t* bg = Wt + (size_t)(n0 + srow) * D_DIM + scol;
    bf16_t* la = &lds_a[(wid * 32) * BK];
    bf16_t* lb = &lds_b[(wid * 32) * BK];

    for (int k0 = 0; k0 < D_DIM; k0 += BK) {
        GLOAD_LDS16(ag + k0,              la);
        GLOAD_LDS16(ag + k0 + 16 * D_DIM, la + 16 * BK);
        GLOAD_LDS16(bg + k0,              lb);
        GLOAD_LDS16(bg + k0 + 16 * D_DIM, lb + 16 * BK);
        __syncthreads();

        bf16x8 af[4], bfr[4];
#pragma unroll
        for (int f = 0; f < 4; f++) {
            af[f]  = *(const bf16x8*)&lds_a[(wm * 64 + f * 16 + lrow) * BK + quad * 8];
            bfr[f] = *(const bf16x8*)&lds_b[(wn * 64 + f * 16 + lrow) * BK + quad * 8];
        }
#pragma unroll
        for (int fm = 0; fm < 4; fm++)
#pragma unroll
            for (int fn = 0; fn < 4; fn++)
                acc[fm][fn] = __builtin_amdgcn_mfma_f32_16x16x32_bf16(
                    af[fm], bfr[fn], acc[fm][fn], 0, 0, 0);
        __syncthreads();
    }

    // epilogue: bias + bf16 store. C layout: col=lane&15, row=quad*4+reg
#pragma unroll
    for (int fn = 0; fn < 4; fn++) {
        int col = n0 + wn * 64 + fn * 16 + lrow;
        float bv = bias[col];
#pragma unroll
        for (int fm = 0; fm < 4; fm++) {
            int rbase = m0 + wm * 64 + fm * 16 + quad * 4;
#pragma unroll
            for (int r = 0; r < 4; r++)
                Out[(size_t)(rbase + r) * D_DIM + col] = (bf16_t)(acc[fm][fn][r] + bv);
        }
    }
}

// ---------------- Kernel D: qk tile + w=exp(tanh) + column reduce ----------------
__global__ __launch_bounds__(256)
void attn_reduce(const bf16_t* __restrict__ Q, const bf16_t* __restrict__ K,
                 float* __restrict__ num, float* __restrict__ den) {
    __shared__ bf16_t lds_a[128 * BK];
    __shared__ bf16_t lds_b[128 * BK];
    __shared__ float red[2][2][128];   // [w|wv][wm][col]

    const int b  = blockIdx.z;
    const int s0 = blockIdx.y * 128;
    const int t0 = blockIdx.x * 128;
    const bf16_t* Qb = Q + (size_t)b * S_DIM * D_DIM;
    const bf16_t* Kb = K + (size_t)b * S_DIM * D_DIM;

    const int tid  = threadIdx.x;
    const int lane = tid & 63;
    const int wid  = tid >> 6;
    const int wm   = wid & 1;
    const int wn   = wid >> 1;
    const int lrow = lane & 15;
    const int quad = lane >> 4;

    f32x4 acc[4][4];
#pragma unroll
    for (int i = 0; i < 4; i++)
#pragma unroll
        for (int j = 0; j < 4; j++) acc[i][j] = (f32x4){0.f, 0.f, 0.f, 0.f};

    const int srow = wid * 32 + (lane >> 2);
    const int scol = (lane & 3) * 8;
    const bf16_t* qg = Qb + (size_t)(s0 + srow) * D_DIM + scol;
    const bf16_t* kg = Kb + (size_t)(t0 + srow) * D_DIM + scol;
    bf16_t* la = &lds_a[(wid * 32) * BK];
    bf16_t* lb = &lds_b[(wid * 32) * BK];

    for (int k0 = 0; k0 < D_DIM; k0 += BK) {
        GLOAD_LDS16(qg + k0,              la);
        GLOAD_LDS16(qg + k0 + 16 * D_DIM, la + 16 * BK);
        GLOAD_LDS16(kg + k0,              lb);
        GLOAD_LDS16(kg + k0 + 16 * D_DIM, lb + 16 * BK);
        __syncthreads();

        bf16x8 af[4], bfr[4];
#pragma unroll
        for (int f = 0; f < 4; f++) {
            af[f]  = *(const bf16x8*)&lds_a[(wm * 64 + f * 16 + lrow) * BK + quad * 8];
            bfr[f] = *(const bf16x8*)&lds_b[(wn * 64 + f * 16 + lrow) * BK + quad * 8];
        }
#pragma unroll
        for (int fm = 0; fm < 4; fm++)
#pragma unroll
            for (int fn = 0; fn < 4; fn++)
                acc[fm][fn] = __builtin_amdgcn_mfma_f32_16x16x32_bf16(
                    af[fm], bfr[fn], acc[fm][fn], 0, 0, 0);
        __syncthreads();
    }

    // w = exp(tanh(qk)); per-column (t) partial sums over the 64 s-rows this wave owns
    float sw[4], swv[4];
#pragma unroll
    for (int fn = 0; fn < 4; fn++) { sw[fn] = 0.f; swv[fn] = 0.f; }
#pragma unroll
    for (int fm = 0; fm < 4; fm++)
#pragma unroll
        for (int fn = 0; fn < 4; fn++)
#pragma unroll
            for (int r = 0; r < 4; r++) {
                float v = acc[fm][fn][r];
                float e2 = __expf(2.f * v);           // tanh via exp; saturates to 1
                float t  = 1.f - 2.f / (e2 + 1.f);
                float w  = __expf(t);
                sw[fn]  += w;
                swv[fn] += w * v;
            }
#pragma unroll
    for (int fn = 0; fn < 4; fn++) {
        sw[fn]  += __shfl_xor(sw[fn], 16);  sw[fn]  += __shfl_xor(sw[fn], 32);
        swv[fn] += __shfl_xor(swv[fn], 16); swv[fn] += __shfl_xor(swv[fn], 32);
    }
    if (quad == 0) {
#pragma unroll
        for (int fn = 0; fn < 4; fn++) {
            red[0][wm][wn * 64 + fn * 16 + lrow] = sw[fn];
            red[1][wm][wn * 64 + fn * 16 + lrow] = swv[fn];
        }
    }
    __syncthreads();
    if (tid < 128) {
        int t = t0 + tid;
        atomicAdd(&den[b * S_DIM + t], red[0][0][tid] + red[0][1][tid]);
        atomicAdd(&num[b * S_DIM + t], red[1][0][tid] + red[1][1][tid]);
    }
}

// ---------------- Kernel E: finalize ----------------
__global__ __launch_bounds__(256)
void finalize(const float* __restrict__ num, const float* __restrict__ den,
              float* __restrict__ out, int n) {
    int i = blockIdx.x * 256 + threadIdx.x;
    if (i < n) out[i] = num[i] / (den[i] + 1e-7f);
}

extern "C" void kernel_launch(void* const* d_in, const int* in_sizes, int n_in,
                              void* d_out, int out_size, void* d_ws, size_t ws_size,
                              hipStream_t stream) {
    (void)in_sizes; (void)n_in; (void)out_size; (void)ws_size;
    const float* x1 = (const float*)d_in[0];
    const float* x2 = (const float*)d_in[1];
    const float* Wq = (const float*)d_in[2];
    const float* bq = (const float*)d_in[3];
    const float* Wk = (const float*)d_in[4];
    const float* bk = (const float*)d_in[5];
    float* out = (float*)d_out;

    char* ws = (char*)d_ws;
    size_t off = 0;
    bf16_t* qb  = (bf16_t*)(ws + off); off += (size_t)M_TOT * D_DIM * 2;   // 25.2 MB
    bf16_t* kb  = (bf16_t*)(ws + off); off += (size_t)M_TOT * D_DIM * 2;
    bf16_t* x1b = (bf16_t*)(ws + off); off += (size_t)M_TOT * D_DIM * 2;
    bf16_t* x2b = (bf16_t*)(ws + off); off += (size_t)M_TOT * D_DIM * 2;
    bf16_t* Wqt = (bf16_t*)(ws + off); off += (size_t)D_DIM * D_DIM * 2;
    bf16_t* Wkt = (bf16_t*)(ws + off); off += (size_t)D_DIM * D_DIM * 2;
    float*  num = (float*)(ws + off);  off += (size_t)M_TOT * 4;
    float*  den = (float*)(ws + off);  off += (size_t)M_TOT * 4;

    hipMemsetAsync(num, 0, (size_t)M_TOT * 4 * 2, stream);

    // exact cover: M_TOT*D_DIM / (256*8) = 6144 blocks per tensor
    cast_inputs<<<dim3(6144, 1, 2), 256, 0, stream>>>(x1, x2, x1b, x2b);
    transpose_weights<<<dim3(24, 24, 2), 256, 0, stream>>>(Wq, Wk, Wqt, Wkt);
    proj_gemm<<<dim3(6, 128, 2), 256, 0, stream>>>(x1b, x2b, Wqt, Wkt, bq, bk, qb, kb);
    attn_reduce<<<dim3(16, 16, 8), 256, 0, stream>>>(qb, kb, num, den);
    finalize<<<dim3((M_TOT + 255) / 256), 256, 0, stream>>>(num, den, out, M_TOT);
}